// Round 1
// baseline (752.090 us; speedup 1.0000x reference)
//
#include <hip/hip_runtime.h>

#define N_ENT 50000
#define N_RELS 500
#define DD 256
#define HD 128
#define EPD 250000
#define ETOT 500000
#define REL_SCALE 2.0943951023931953f  // pi / 1.5

// ---------------- degree count (atomic float, exact for small ints) --------
__global__ __launch_bounds__(256) void k_deg(const int* __restrict__ ei,
                                             float* __restrict__ deg) {
    int e = blockIdx.x * 256 + threadIdx.x;
    if (e >= ETOT) return;
    int row = ei[e];                // edge_index[0][e]
    int dir = e >= EPD;
    if ((unsigned)row < N_ENT) atomicAdd(deg + dir * N_ENT + row, 1.0f);
}

// ---------------- deg -> deg^-0.5 in place ---------------------------------
__global__ __launch_bounds__(256) void k_dinv(float* __restrict__ deg) {
    int i = blockIdx.x * 256 + threadIdx.x;
    if (i >= 2 * N_ENT) return;
    float v = deg[i];
    deg[i] = (v > 0.0f) ? rsqrtf(v) : 0.0f;
}

// ---------------- per-edge transform + scatter (wave per edge) -------------
__global__ __launch_bounds__(256) void k_msg(const int* __restrict__ ei,
                                             const int* __restrict__ et,
                                             const float* __restrict__ x,
                                             const float* __restrict__ rel,
                                             const float* __restrict__ dinv,
                                             float* __restrict__ A) {
    int wid  = (blockIdx.x * 256 + threadIdx.x) >> 6;  // edge id
    int lane = threadIdx.x & 63;
    if (wid >= ETOT) return;
    int row = ei[wid];
    int col = ei[ETOT + wid];
    int t   = et[wid];
    int dir = wid >= EPD;
    if ((unsigned)row >= N_ENT || (unsigned)col >= N_ENT) return;
    const float* dv = dinv + dir * N_ENT;
    float norm = dv[row] * dv[col];
    const float* xr = x + (size_t)col * DD;
    const float* rr = rel + (size_t)t * HD;
    float* Ar = A + (size_t)(dir * N_ENT + row) * DD;
#pragma unroll
    for (int h = 0; h < 2; ++h) {
        int j = lane + 64 * h;          // 0..127
        float re = xr[j];
        float im = xr[j + HD];
        float s, c;
        __sincosf(rr[j] * REL_SCALE, &s, &c);
        atomicAdd(Ar + j,      norm * (re * c + im * s));
        atomicAdd(Ar + j + HD, norm * (re * s - im * c));
    }
}

// ---------------- build concatenated weight [w_in; w_out; W'loop] ----------
__global__ __launch_bounds__(256) void k_wcat(const float* __restrict__ w_in,
                                              const float* __restrict__ w_out,
                                              const float* __restrict__ w_loop,
                                              const float* __restrict__ loop_rel,
                                              float* __restrict__ W) {
    int idx = blockIdx.x * 256 + threadIdx.x;  // 768*256
    if (idx >= 768 * 256) return;
    int k = idx >> 8, c = idx & 255;
    float v;
    if (k < 256) {
        v = w_in[k * 256 + c];
    } else if (k < 512) {
        v = w_out[(k - 256) * 256 + c];
    } else {
        int j = k - 512;
        // loop_res = transform(x, loop_rel) @ w_loop = x @ W'
        // W'[j][c]      =  c_j*w[j][c] + s_j*w[j+128][c]        (j < 128)
        // W'[j+128][c]  =  s_j*w[j][c] - c_j*w[j+128][c]
        int jj = (j < HD) ? j : j - HD;
        float s, co;
        __sincosf(loop_rel[jj] * REL_SCALE, &s, &co);
        float w0 = w_loop[jj * 256 + c];
        float w1 = w_loop[(jj + HD) * 256 + c];
        v = (j < HD) ? (co * w0 + s * w1) : (s * w0 - co * w1);
    }
    W[idx] = v;
}

// ---------------- fused GEMM: out = [Ain|Aout|x](50000x768) @ W(768x256)/3 --
__global__ __launch_bounds__(256) void k_gemm(const float* __restrict__ Ain,
                                              const float* __restrict__ Aout,
                                              const float* __restrict__ x,
                                              const float* __restrict__ W,
                                              float* __restrict__ out) {
    __shared__ float As[16][128];   // [k][m]
    __shared__ float Bs[16][128];   // [k][n]
    int tid = threadIdx.x;
    int tx = tid & 15, ty = tid >> 4;
    int m0 = blockIdx.x * 128, n0 = blockIdx.y * 128;
    float acc[8][8] = {};

    for (int k0 = 0; k0 < 768; k0 += 16) {
        const float* base = (k0 < 256) ? Ain : ((k0 < 512) ? Aout : x);
        int kk0 = k0 & 255;
        {   // A tile: 128 rows x 16 k
            int ml = tid >> 1, kl = (tid & 1) * 8;
            int m = m0 + ml;
            float v[8];
            if (m < N_ENT) {
                const float4* p = (const float4*)(base + (size_t)m * DD + kk0 + kl);
                float4 v0 = p[0], v1 = p[1];
                v[0]=v0.x; v[1]=v0.y; v[2]=v0.z; v[3]=v0.w;
                v[4]=v1.x; v[5]=v1.y; v[6]=v1.z; v[7]=v1.w;
            } else {
#pragma unroll
                for (int i = 0; i < 8; ++i) v[i] = 0.0f;
            }
#pragma unroll
            for (int i = 0; i < 8; ++i) As[kl + i][ml] = v[i];
        }
        {   // B tile: 16 k x 128 n
            int kl = tid >> 4, nl = (tid & 15) * 8;
            const float4* p = (const float4*)(W + (size_t)(k0 + kl) * DD + n0 + nl);
            *(float4*)&Bs[kl][nl]     = p[0];
            *(float4*)&Bs[kl][nl + 4] = p[1];
        }
        __syncthreads();
#pragma unroll
        for (int kk = 0; kk < 16; ++kk) {
            float a[8], b[8];
            *(float4*)&a[0] = *(const float4*)&As[kk][ty * 8];
            *(float4*)&a[4] = *(const float4*)&As[kk][ty * 8 + 4];
            *(float4*)&b[0] = *(const float4*)&Bs[kk][tx * 8];
            *(float4*)&b[4] = *(const float4*)&Bs[kk][tx * 8 + 4];
#pragma unroll
            for (int i = 0; i < 8; ++i)
#pragma unroll
                for (int j = 0; j < 8; ++j)
                    acc[i][j] += a[i] * b[j];
        }
        __syncthreads();
    }

#pragma unroll
    for (int i = 0; i < 8; ++i) {
        int m = m0 + ty * 8 + i;
        if (m >= N_ENT) break;
        float* po = out + (size_t)m * DD + n0 + tx * 8;
        float4 o0, o1;
        o0.x = acc[i][0] * (1.0f/3.0f); o0.y = acc[i][1] * (1.0f/3.0f);
        o0.z = acc[i][2] * (1.0f/3.0f); o0.w = acc[i][3] * (1.0f/3.0f);
        o1.x = acc[i][4] * (1.0f/3.0f); o1.y = acc[i][5] * (1.0f/3.0f);
        o1.z = acc[i][6] * (1.0f/3.0f); o1.w = acc[i][7] * (1.0f/3.0f);
        *(float4*)(po)     = o0;
        *(float4*)(po + 4) = o1;
    }
}

// ---------------- rel_out = rel_embed @ w_rel ------------------------------
__global__ __launch_bounds__(256) void k_relout(const float* __restrict__ rel,
                                                const float* __restrict__ w_rel,
                                                float* __restrict__ out) {
    int idx = blockIdx.x * 256 + threadIdx.x;  // 500*128
    if (idx >= N_RELS * HD) return;
    int i = idx >> 7, c = idx & 127;
    float acc = 0.0f;
    for (int k = 0; k < HD; ++k) acc += rel[i * HD + k] * w_rel[k * HD + c];
    out[idx] = acc;
}

extern "C" void kernel_launch(void* const* d_in, const int* in_sizes, int n_in,
                              void* d_out, int out_size, void* d_ws, size_t ws_size,
                              hipStream_t stream) {
    const float* x        = (const float*)d_in[0];
    const int*   ei       = (const int*)d_in[1];
    const int*   et       = (const int*)d_in[2];
    const float* rel      = (const float*)d_in[3];
    const float* w_loop   = (const float*)d_in[4];
    const float* w_in     = (const float*)d_in[5];
    const float* w_out    = (const float*)d_in[6];
    const float* w_rel    = (const float*)d_in[7];
    const float* loop_rel = (const float*)d_in[8];

    float* A    = (float*)d_ws;                      // [2][N_ENT][DD]
    float* deg  = A + (size_t)2 * N_ENT * DD;        // [2][N_ENT]
    float* Wcat = deg + 2 * N_ENT;                   // [768][256]

    float* out     = (float*)d_out;                  // [N_ENT][DD]
    float* rel_out = out + (size_t)N_ENT * DD;       // [500][128]

    // zero accumulators (A + deg are contiguous)
    hipMemsetAsync(A, 0, ((size_t)2 * N_ENT * DD + 2 * N_ENT) * sizeof(float), stream);

    k_deg <<<(ETOT + 255) / 256, 256, 0, stream>>>(ei, deg);
    k_dinv<<<(2 * N_ENT + 255) / 256, 256, 0, stream>>>(deg);
    k_msg <<<ETOT / 4, 256, 0, stream>>>(ei, et, x, rel, deg, A);
    k_wcat<<<(768 * 256) / 256, 256, 0, stream>>>(w_in, w_out, w_loop, loop_rel, Wcat);

    dim3 gg((N_ENT + 127) / 128, 2);
    k_gemm<<<gg, 256, 0, stream>>>(A, A + (size_t)N_ENT * DD, x, Wcat, out);

    k_relout<<<(N_RELS * HD + 255) / 256, 256, 0, stream>>>(rel, w_rel, rel_out);
}

// Round 2
// 215.756 us; speedup vs baseline: 3.4858x; 3.4858x over previous
//
#include <hip/hip_runtime.h>

#define N_ENT 50000
#define MPAD  50048            // 391*128, padded rows for GEMM staging
#define N_RELS 500
#define DD 256
#define HD 128
#define EPD 250000
#define ETOT 500000
#define NK (2 * N_ENT)         // (dir,row) keys
#define NBLK 98                // ceil(NK/1024)
#define REL_SCALE 2.0943951023931953f  // pi / 1.5

typedef unsigned short ushort_t;
typedef unsigned int uint_t;
typedef __attribute__((ext_vector_type(8))) short short8v;
typedef __attribute__((ext_vector_type(4))) float f32x4;

__device__ inline ushort_t f2bf(float f) {
    union { float f; unsigned u; } v; v.f = f;
    unsigned r = v.u + 0x7FFF + ((v.u >> 16) & 1);
    return (ushort_t)(r >> 16);
}

#define GLOAD_LDS16(g, l) __builtin_amdgcn_global_load_lds( \
    (const __attribute__((address_space(1))) unsigned int*)(g), \
    (__attribute__((address_space(3))) unsigned int*)(l), 16, 0, 0)

// ---------------- int degree histogram per (dir,row) -----------------------
__global__ __launch_bounds__(256) void k_deg(const int* __restrict__ ei,
                                             int* __restrict__ deg) {
    int e = blockIdx.x * 256 + threadIdx.x;
    if (e >= ETOT) return;
    int key = (e >= EPD ? N_ENT : 0) + ei[e];
    atomicAdd(deg + key, 1);
}

// ---------------- dinv = deg^-0.5 ------------------------------------------
__global__ __launch_bounds__(256) void k_dinv(const int* __restrict__ deg,
                                              float* __restrict__ dinv) {
    int i = blockIdx.x * 256 + threadIdx.x;
    if (i >= NK) return;
    int d = deg[i];
    dinv[i] = (d > 0) ? rsqrtf((float)d) : 0.0f;
}

// ---------------- exclusive scan over 100K (3 kernels) ---------------------
__global__ __launch_bounds__(256) void k_scan1(const int* __restrict__ deg,
                                               int* __restrict__ off,
                                               int* __restrict__ bsum) {
    __shared__ int wsum[4];
    int b = blockIdx.x, t = threadIdx.x;
    int base = b * 1024 + t * 4;
    int v[4];
#pragma unroll
    for (int i = 0; i < 4; ++i) v[i] = (base + i < NK) ? deg[base + i] : 0;
    int tsum = v[0] + v[1] + v[2] + v[3];
    int lane = t & 63, w = t >> 6;
    int incl = tsum;
    for (int d = 1; d < 64; d <<= 1) {
        int y = __shfl_up(incl, d);
        if (lane >= d) incl += y;
    }
    if (lane == 63) wsum[w] = incl;
    __syncthreads();
    int woff = 0;
    for (int k = 0; k < w; ++k) woff += wsum[k];
    int run = woff + incl - tsum;
#pragma unroll
    for (int i = 0; i < 4; ++i) {
        if (base + i < NK) off[base + i] = run;
        run += v[i];
    }
    if (t == 255) bsum[b] = woff + incl;   // block total
}

__global__ void k_scan2(int* __restrict__ bsum) {
    __shared__ int s[NBLK];
    int t = threadIdx.x;
    if (t < NBLK) s[t] = bsum[t];
    __syncthreads();
    if (t == 0) {
        int c = 0;
        for (int i = 0; i < NBLK; ++i) { int x = s[i]; s[i] = c; c += x; }
    }
    __syncthreads();
    if (t < NBLK) bsum[t] = s[t];
}

__global__ __launch_bounds__(256) void k_scan3(int* __restrict__ off,
                                               const int* __restrict__ bsum) {
    int i = blockIdx.x * 256 + threadIdx.x;
    if (i >= NK) return;
    off[i] += bsum[i >> 10];
}

// ---------------- bucket edges by (dir,row): 1 atomic per edge -------------
__global__ __launch_bounds__(256) void k_bucket(const int* __restrict__ ei,
                                                const int* __restrict__ et,
                                                const int* __restrict__ off,
                                                int* __restrict__ cnt,
                                                uint_t* __restrict__ bucket) {
    int e = blockIdx.x * 256 + threadIdx.x;
    if (e >= ETOT) return;
    int key = (e >= EPD ? N_ENT : 0) + ei[e];
    int pos = off[key] + atomicAdd(cnt + key, 1);
    uint_t col = (uint_t)ei[ETOT + e];
    uint_t t   = (uint_t)et[e];
    bucket[pos] = col | (t << 16);         // col < 65536, t < 512
}

// ---------------- gather: one wave per (dir,row), write bf16 ---------------
__global__ __launch_bounds__(256) void k_gather(const uint_t* __restrict__ bucket,
                                                const int* __restrict__ off,
                                                const int* __restrict__ deg,
                                                const float* __restrict__ dinv,
                                                const float* __restrict__ x,
                                                const float* __restrict__ rel,
                                                ushort_t* __restrict__ A) {
    int wid  = (blockIdx.x * 256 + threadIdx.x) >> 6;   // (dir,row) key
    int lane = threadIdx.x & 63;
    if (wid >= NK) return;
    int dir = (wid >= N_ENT);
    int row = wid - dir * N_ENT;
    float dv_r = dinv[wid];
    int start = off[wid], n = deg[wid];
    const float* dvc = dinv + dir * N_ENT;
    float a0 = 0.f, a1 = 0.f, a2 = 0.f, a3 = 0.f;
    for (int i = 0; i < n; ++i) {
        uint_t p = bucket[start + i];
        int col = (int)(p & 0xFFFFu);
        int t   = (int)(p >> 16);
        float norm = dv_r * dvc[col];
        const float* xr = x + (size_t)col * DD;
        const float* rr = rel + (size_t)t * HD;
        float re0 = xr[lane],      im0 = xr[lane + HD];
        float re1 = xr[lane + 64], im1 = xr[lane + 64 + HD];
        float s0, c0, s1, c1;
        __sincosf(rr[lane] * REL_SCALE, &s0, &c0);
        __sincosf(rr[lane + 64] * REL_SCALE, &s1, &c1);
        a0 += norm * (re0 * c0 + im0 * s0);
        a1 += norm * (re1 * c1 + im1 * s1);
        a2 += norm * (re0 * s0 - im0 * c0);
        a3 += norm * (re1 * s1 - im1 * c1);
    }
    ushort_t* Ar = A + (size_t)(dir * MPAD + row) * DD;
    Ar[lane]           = f2bf(a0);
    Ar[lane + 64]      = f2bf(a1);
    Ar[lane + 128]     = f2bf(a2);
    Ar[lane + 192]     = f2bf(a3);
}

// ---------------- x -> bf16 ------------------------------------------------
__global__ __launch_bounds__(256) void k_castx(const float* __restrict__ x,
                                               ushort_t* __restrict__ xb) {
    int i = blockIdx.x * 256 + threadIdx.x;   // one float4 each
    if (i >= N_ENT * DD / 4) return;
    float4 v = ((const float4*)x)[i];
    ushort_t o[4] = { f2bf(v.x), f2bf(v.y), f2bf(v.z), f2bf(v.w) };
    *(ulong1*)&xb[i * 4] = *(ulong1*)o;
}

// ---------------- fused weight, transposed: Wt[256n][768k], bf16 -----------
__global__ __launch_bounds__(256) void k_wcat(const float* __restrict__ w_in,
                                              const float* __restrict__ w_out,
                                              const float* __restrict__ w_loop,
                                              const float* __restrict__ loop_rel,
                                              ushort_t* __restrict__ Wt) {
    int idx = blockIdx.x * 256 + threadIdx.x;   // 256*768
    if (idx >= 256 * 768) return;
    int n = idx / 768, k = idx - n * 768;
    float v;
    if (k < 256) {
        v = w_in[k * 256 + n];
    } else if (k < 512) {
        v = w_out[(k - 256) * 256 + n];
    } else {
        int j = k - 512;
        int jj = (j < HD) ? j : j - HD;
        float s, c;
        __sincosf(loop_rel[jj] * REL_SCALE, &s, &c);
        float w0 = w_loop[jj * 256 + n];
        float w1 = w_loop[(jj + HD) * 256 + n];
        v = (j < HD) ? (c * w0 + s * w1) : (s * w0 - c * w1);
    }
    Wt[idx] = f2bf(v);
}

// ---------------- MFMA GEMM: out = [Ain|Aout|xb](M x 768) @ Wt^T / 3 -------
__global__ __launch_bounds__(256) void k_gemm(const ushort_t* __restrict__ Ain,
                                              const ushort_t* __restrict__ Aout,
                                              const ushort_t* __restrict__ xb,
                                              const ushort_t* __restrict__ Wt,
                                              float* __restrict__ out) {
    __shared__ ushort_t Al[128 * 32];
    __shared__ ushort_t Bl[128 * 32];
    int tid = threadIdx.x;
    int m0 = blockIdx.x * 128, n0 = blockIdx.y * 128;
    int lane = tid & 63, wv = tid >> 6;
    int wr = (wv >> 1) * 64, wc = (wv & 1) * 64;
    int srow = tid >> 2;            // 0..63
    int scol = (tid & 3) * 8;       // k elems
    f32x4 zero = {0.f, 0.f, 0.f, 0.f};
    f32x4 acc[4][4];
#pragma unroll
    for (int i = 0; i < 4; ++i)
#pragma unroll
        for (int j = 0; j < 4; ++j) acc[i][j] = zero;

    for (int k0 = 0; k0 < 768; k0 += 32) {
        const ushort_t* baseA = (k0 < 256) ? Ain : ((k0 < 512) ? Aout : xb);
        int kk0 = k0 & 255;
        GLOAD_LDS16(baseA + (size_t)(m0 + srow) * DD + kk0 + scol,      &Al[tid * 8]);
        GLOAD_LDS16(baseA + (size_t)(m0 + 64 + srow) * DD + kk0 + scol, &Al[2048 + tid * 8]);
        GLOAD_LDS16(Wt + (size_t)(n0 + srow) * 768 + k0 + scol,         &Bl[tid * 8]);
        GLOAD_LDS16(Wt + (size_t)(n0 + 64 + srow) * 768 + k0 + scol,    &Bl[2048 + tid * 8]);
        __syncthreads();
        int r = lane & 15, h = lane >> 4;
        short8v a[4], b[4];
#pragma unroll
        for (int i = 0; i < 4; ++i) a[i] = *(const short8v*)&Al[(wr + i * 16 + r) * 32 + h * 8];
#pragma unroll
        for (int j = 0; j < 4; ++j) b[j] = *(const short8v*)&Bl[(wc + j * 16 + r) * 32 + h * 8];
#pragma unroll
        for (int i = 0; i < 4; ++i)
#pragma unroll
            for (int j = 0; j < 4; ++j)
                acc[i][j] = __builtin_amdgcn_mfma_f32_16x16x32_bf16(a[i], b[j], acc[i][j], 0, 0, 0);
        __syncthreads();
    }
    // C/D: col = lane&15, row = (lane>>4)*4 + reg   [m89-verified]
    int cn = lane & 15, rq = lane >> 4;
#pragma unroll
    for (int i = 0; i < 4; ++i)
#pragma unroll
        for (int j = 0; j < 4; ++j)
#pragma unroll
            for (int q = 0; q < 4; ++q) {
                int m = m0 + wr + i * 16 + rq * 4 + q;
                if (m < N_ENT) {
                    int n = n0 + wc + j * 16 + cn;
                    out[(size_t)m * DD + n] = acc[i][j][q] * (1.0f / 3.0f);
                }
            }
}

// ---------------- rel_out = rel_embed @ w_rel ------------------------------
__global__ __launch_bounds__(256) void k_relout(const float* __restrict__ rel,
                                                const float* __restrict__ w_rel,
                                                float* __restrict__ out) {
    int idx = blockIdx.x * 256 + threadIdx.x;
    if (idx >= N_RELS * HD) return;
    int i = idx >> 7, c = idx & 127;
    float acc = 0.0f;
    for (int k = 0; k < HD; ++k) acc += rel[i * HD + k] * w_rel[k * HD + c];
    out[idx] = acc;
}

extern "C" void kernel_launch(void* const* d_in, const int* in_sizes, int n_in,
                              void* d_out, int out_size, void* d_ws, size_t ws_size,
                              hipStream_t stream) {
    const float* x        = (const float*)d_in[0];
    const int*   ei       = (const int*)d_in[1];
    const int*   et       = (const int*)d_in[2];
    const float* rel      = (const float*)d_in[3];
    const float* w_loop   = (const float*)d_in[4];
    const float* w_in     = (const float*)d_in[5];
    const float* w_out    = (const float*)d_in[6];
    const float* w_rel    = (const float*)d_in[7];
    const float* loop_rel = (const float*)d_in[8];

    char* w = (char*)d_ws;
    ushort_t* Ain  = (ushort_t*)w;  w += (size_t)2 * MPAD * DD * 2;
    ushort_t* xb   = (ushort_t*)w;  w += (size_t)MPAD * DD * 2;
    ushort_t* Wt   = (ushort_t*)w;  w += 256 * 768 * 2;
    int* deg_i     = (int*)w;       w += NK * 4;
    int* cnt       = (int*)w;       w += NK * 4;
    int* off       = (int*)w;       w += NK * 4;
    int* bsum      = (int*)w;       w += 128 * 4;
    float* dinv    = (float*)w;     w += NK * 4;
    uint_t* bucket = (uint_t*)w;    w += (size_t)ETOT * 4;
    ushort_t* Aout = Ain + (size_t)MPAD * DD;

    float* out     = (float*)d_out;
    float* rel_out = out + (size_t)N_ENT * DD;

    // zero deg_i + cnt (adjacent)
    hipMemsetAsync(deg_i, 0, (size_t)2 * NK * 4, stream);

    k_deg   <<<(ETOT + 255) / 256, 256, 0, stream>>>(ei, deg_i);
    k_dinv  <<<(NK + 255) / 256, 256, 0, stream>>>(deg_i, dinv);
    k_scan1 <<<NBLK, 256, 0, stream>>>(deg_i, off, bsum);
    k_scan2 <<<1, 128, 0, stream>>>(bsum);
    k_scan3 <<<(NK + 255) / 256, 256, 0, stream>>>(off, bsum);
    k_bucket<<<(ETOT + 255) / 256, 256, 0, stream>>>(ei, et, off, cnt, bucket);
    k_gather<<<(NK + 3) / 4, 256, 0, stream>>>(bucket, off, deg_i, dinv, x, rel, Ain);
    k_castx <<<(N_ENT * DD / 4 + 255) / 256, 256, 0, stream>>>(x, xb);
    k_wcat  <<<(256 * 768) / 256, 256, 0, stream>>>(w_in, w_out, w_loop, loop_rel, Wt);

    dim3 gg((MPAD) / 128, 2);
    k_gemm  <<<gg, 256, 0, stream>>>(Ain, Aout, xb, Wt, out);
    k_relout<<<(N_RELS * HD + 255) / 256, 256, 0, stream>>>(rel, w_rel, rel_out);
}

// Round 3
// 186.485 us; speedup vs baseline: 4.0330x; 1.1570x over previous
//
#include <hip/hip_runtime.h>

#define N_ENT 50000
#define MPAD  50048            // 391*128, padded rows for GEMM staging
#define N_RELS 500
#define DD 256
#define HD 128
#define EPD 250000
#define ETOT 500000
#define NK (2 * N_ENT)         // (dir,row) keys
#define NBLK 98                // ceil(NK/1024)
#define REL_SCALE 2.0943951023931953f  // pi / 1.5

typedef unsigned short ushort_t;
typedef unsigned int uint_t;
typedef __attribute__((ext_vector_type(8))) short short8v;
typedef __attribute__((ext_vector_type(4))) float f32x4;

__device__ inline ushort_t f2bf(float f) {
    union { float f; unsigned u; } v; v.f = f;
    unsigned r = v.u + 0x7FFF + ((v.u >> 16) & 1);
    return (ushort_t)(r >> 16);
}
__device__ inline float bfl(uint_t w) { return __uint_as_float(w << 16); }
__device__ inline float bfh(uint_t w) { return __uint_as_float(w & 0xFFFF0000u); }

#define GLOAD_LDS16(g, l) __builtin_amdgcn_global_load_lds( \
    (const __attribute__((address_space(1))) unsigned int*)(g), \
    (__attribute__((address_space(3))) unsigned int*)(l), 16, 0, 0)

// ---------------- int degree histogram per (dir,row) -----------------------
__global__ __launch_bounds__(256) void k_deg(const int* __restrict__ ei,
                                             int* __restrict__ deg) {
    int e = blockIdx.x * 256 + threadIdx.x;
    if (e >= ETOT) return;
    int key = (e >= EPD ? N_ENT : 0) + ei[e];
    atomicAdd(deg + key, 1);
}

// ---------------- per-block exclusive scan + dinv --------------------------
__global__ __launch_bounds__(256) void k_scan1(const int* __restrict__ deg,
                                               int* __restrict__ off,
                                               int* __restrict__ bsum,
                                               float* __restrict__ dinv) {
    __shared__ int wsum[4];
    int b = blockIdx.x, t = threadIdx.x;
    int base = b * 1024 + t * 4;
    int v[4];
#pragma unroll
    for (int i = 0; i < 4; ++i) v[i] = (base + i < NK) ? deg[base + i] : 0;
    int tsum = v[0] + v[1] + v[2] + v[3];
    int lane = t & 63, w = t >> 6;
    int incl = tsum;
    for (int d = 1; d < 64; d <<= 1) {
        int y = __shfl_up(incl, d);
        if (lane >= d) incl += y;
    }
    if (lane == 63) wsum[w] = incl;
    __syncthreads();
    int woff = 0;
    for (int k = 0; k < w; ++k) woff += wsum[k];
    int run = woff + incl - tsum;
#pragma unroll
    for (int i = 0; i < 4; ++i) {
        if (base + i < NK) {
            off[base + i] = run;
            dinv[base + i] = (v[i] > 0) ? rsqrtf((float)v[i]) : 0.0f;
        }
        run += v[i];
    }
    if (t == 255) bsum[b] = woff + incl;   // block total
}

__global__ void k_scan2(int* __restrict__ bsum) {
    __shared__ int s[NBLK];
    int t = threadIdx.x;
    if (t < NBLK) s[t] = bsum[t];
    __syncthreads();
    if (t == 0) {
        int c = 0;
        for (int i = 0; i < NBLK; ++i) { int x = s[i]; s[i] = c; c += x; }
    }
    __syncthreads();
    if (t < NBLK) bsum[t] = s[t];
}

// ---------------- bucket edges by (dir,row): 1 atomic per edge -------------
__global__ __launch_bounds__(256) void k_bucket(const int* __restrict__ ei,
                                                const int* __restrict__ et,
                                                const int* __restrict__ off,
                                                const int* __restrict__ bsum,
                                                int* __restrict__ cnt,
                                                uint_t* __restrict__ bucket) {
    int e = blockIdx.x * 256 + threadIdx.x;
    if (e >= ETOT) return;
    int key = (e >= EPD ? N_ENT : 0) + ei[e];
    int pos = off[key] + bsum[key >> 10] + atomicAdd(cnt + key, 1);
    uint_t col = (uint_t)ei[ETOT + e];
    uint_t t   = (uint_t)et[e];
    bucket[pos] = col | (t << 16);         // col < 65536, t < 512
}

// ---------------- prep: castx (12500 blk) + utab (250) + wcat (768) --------
__global__ __launch_bounds__(256) void k_prep(const float* __restrict__ x,
                                              const float* __restrict__ rel,
                                              const float* __restrict__ w_in,
                                              const float* __restrict__ w_out,
                                              const float* __restrict__ w_loop,
                                              const float* __restrict__ loop_rel,
                                              ushort_t* __restrict__ xb,
                                              uint_t* __restrict__ u,
                                              ushort_t* __restrict__ Wt) {
    int b = blockIdx.x, tid = threadIdx.x;
    if (b < 12500) {                       // x -> bf16, one float4 per thread
        int i = b * 256 + tid;             // < 3,200,000
        float4 v = ((const float4*)x)[i];
        ushort_t o[4] = { f2bf(v.x), f2bf(v.y), f2bf(v.z), f2bf(v.w) };
        *(uint2*)&xb[i * 4] = *(uint2*)o;
    } else if (b < 12750) {                // u[t][j] = pack(cos, sin)
        int idx = (b - 12500) * 256 + tid; // < 64000 = 500*128
        float s, c;
        __sincosf(rel[idx] * REL_SCALE, &s, &c);
        u[idx] = (uint_t)f2bf(c) | ((uint_t)f2bf(s) << 16);
    } else {                               // Wt[256n][768k] bf16
        int idx = (b - 12750) * 256 + tid; // < 196608
        int n = idx / 768, k = idx - n * 768;
        float v;
        if (k < 256) {
            v = w_in[k * 256 + n];
        } else if (k < 512) {
            v = w_out[(k - 256) * 256 + n];
        } else {
            int j = k - 512;
            int jj = (j < HD) ? j : j - HD;
            float s, c;
            __sincosf(loop_rel[jj] * REL_SCALE, &s, &c);
            float w0 = w_loop[jj * 256 + n];
            float w1 = w_loop[(jj + HD) * 256 + n];
            v = (j < HD) ? (c * w0 + s * w1) : (s * w0 - c * w1);
        }
        Wt[idx] = f2bf(v);
    }
}

// ---------------- gather: one wave per (dir,row), bf16 in/out --------------
// T(z) = e^{i*theta} * conj(z):  out_lo = re*c + im*s ; out_hi = re*s - im*c
// lane l owns x elems 4l..4l+3; partner (re<->im) is lane l^32.
// term = partner*s + sgn*own*c, sgn = (l>=32) ? -1 : +1.
__global__ __launch_bounds__(256) void k_gather(const uint_t* __restrict__ bucket,
                                                const int* __restrict__ off,
                                                const int* __restrict__ bsum,
                                                const int* __restrict__ deg,
                                                const float* __restrict__ dinv,
                                                const ushort_t* __restrict__ xb,
                                                const uint_t* __restrict__ u,
                                                ushort_t* __restrict__ A) {
    int wid  = (blockIdx.x * 256 + threadIdx.x) >> 6;
    int lane = threadIdx.x & 63;
    if (wid >= NK) return;
    int dir = (wid >= N_ENT);
    int row = wid - dir * N_ENT;
    float dv_r = dinv[wid];
    int start = off[wid] + bsum[wid >> 10];
    int n = deg[wid];
    const float* dvc = dinv + dir * N_ENT;
    int l31 = lane & 31;
    float sgn = (lane >= 32) ? -1.0f : 1.0f;
    float acc0 = 0.f, acc1 = 0.f, acc2 = 0.f, acc3 = 0.f;

#define EDGE_MATH(ow, qq, nm) do {                                          \
        uint_t px = (uint_t)__shfl_xor((int)ow.x, 32);                      \
        uint_t py = (uint_t)__shfl_xor((int)ow.y, 32);                      \
        float t0 = bfl(px) * bfh(qq.x) + sgn * (bfl(ow.x) * bfl(qq.x));     \
        float t1 = bfh(px) * bfh(qq.y) + sgn * (bfh(ow.x) * bfl(qq.y));     \
        float t2 = bfl(py) * bfh(qq.z) + sgn * (bfl(ow.y) * bfl(qq.z));     \
        float t3 = bfh(py) * bfh(qq.w) + sgn * (bfh(ow.y) * bfl(qq.w));     \
        acc0 += nm * t0; acc1 += nm * t1; acc2 += nm * t2; acc3 += nm * t3; \
    } while (0)

    int i = 0;
    for (; i + 1 < n; i += 2) {
        uint_t p0 = bucket[start + i];
        uint_t p1 = bucket[start + i + 1];
        int c0 = p0 & 0xFFFF, t0i = p0 >> 16;
        int c1 = p1 & 0xFFFF, t1i = p1 >> 16;
        float nm0 = dv_r * dvc[c0];
        float nm1 = dv_r * dvc[c1];
        uint2 o0 = *(const uint2*)(xb + (size_t)c0 * DD + lane * 4);
        uint2 o1 = *(const uint2*)(xb + (size_t)c1 * DD + lane * 4);
        uint4 q0 = *(const uint4*)(u + (size_t)t0i * HD + l31 * 4);
        uint4 q1 = *(const uint4*)(u + (size_t)t1i * HD + l31 * 4);
        EDGE_MATH(o0, q0, nm0);
        EDGE_MATH(o1, q1, nm1);
    }
    if (i < n) {
        uint_t p0 = bucket[start + i];
        int c0 = p0 & 0xFFFF, t0i = p0 >> 16;
        float nm0 = dv_r * dvc[c0];
        uint2 o0 = *(const uint2*)(xb + (size_t)c0 * DD + lane * 4);
        uint4 q0 = *(const uint4*)(u + (size_t)t0i * HD + l31 * 4);
        EDGE_MATH(o0, q0, nm0);
    }
#undef EDGE_MATH

    uint_t r0 = (uint_t)f2bf(acc0) | ((uint_t)f2bf(acc1) << 16);
    uint_t r1 = (uint_t)f2bf(acc2) | ((uint_t)f2bf(acc3) << 16);
    uint2 rr; rr.x = r0; rr.y = r1;
    *(uint2*)(A + (size_t)(dir * MPAD + row) * DD + lane * 4) = rr;
}

// ---------------- MFMA GEMM: out = [Ain|Aout|xb](M x 768) @ Wt^T / 3 -------
__global__ __launch_bounds__(256) void k_gemm(const ushort_t* __restrict__ Ain,
                                              const ushort_t* __restrict__ Aout,
                                              const ushort_t* __restrict__ xb,
                                              const ushort_t* __restrict__ Wt,
                                              float* __restrict__ out) {
    __shared__ ushort_t Al[128 * 32];
    __shared__ ushort_t Bl[128 * 32];
    int tid = threadIdx.x;
    int m0 = blockIdx.x * 128, n0 = blockIdx.y * 128;
    int lane = tid & 63, wv = tid >> 6;
    int wr = (wv >> 1) * 64, wc = (wv & 1) * 64;
    int srow = tid >> 2;            // 0..63
    int scol = (tid & 3) * 8;       // k elems
    f32x4 zero = {0.f, 0.f, 0.f, 0.f};
    f32x4 acc[4][4];
#pragma unroll
    for (int i = 0; i < 4; ++i)
#pragma unroll
        for (int j = 0; j < 4; ++j) acc[i][j] = zero;

    for (int k0 = 0; k0 < 768; k0 += 32) {
        const ushort_t* baseA = (k0 < 256) ? Ain : ((k0 < 512) ? Aout : xb);
        int kk0 = k0 & 255;
        GLOAD_LDS16(baseA + (size_t)(m0 + srow) * DD + kk0 + scol,      &Al[tid * 8]);
        GLOAD_LDS16(baseA + (size_t)(m0 + 64 + srow) * DD + kk0 + scol, &Al[2048 + tid * 8]);
        GLOAD_LDS16(Wt + (size_t)(n0 + srow) * 768 + k0 + scol,         &Bl[tid * 8]);
        GLOAD_LDS16(Wt + (size_t)(n0 + 64 + srow) * 768 + k0 + scol,    &Bl[2048 + tid * 8]);
        __syncthreads();
        int r = lane & 15, h = lane >> 4;
        short8v a[4], b[4];
#pragma unroll
        for (int i = 0; i < 4; ++i) a[i] = *(const short8v*)&Al[(wr + i * 16 + r) * 32 + h * 8];
#pragma unroll
        for (int j = 0; j < 4; ++j) b[j] = *(const short8v*)&Bl[(wc + j * 16 + r) * 32 + h * 8];
#pragma unroll
        for (int i = 0; i < 4; ++i)
#pragma unroll
            for (int j = 0; j < 4; ++j)
                acc[i][j] = __builtin_amdgcn_mfma_f32_16x16x32_bf16(a[i], b[j], acc[i][j], 0, 0, 0);
        __syncthreads();
    }
    // C/D: col = lane&15, row = (lane>>4)*4 + reg   [m89-verified]
    int cn = lane & 15, rq = lane >> 4;
#pragma unroll
    for (int i = 0; i < 4; ++i)
#pragma unroll
        for (int j = 0; j < 4; ++j)
#pragma unroll
            for (int q = 0; q < 4; ++q) {
                int m = m0 + wr + i * 16 + rq * 4 + q;
                if (m < N_ENT) {
                    int n = n0 + wc + j * 16 + cn;
                    out[(size_t)m * DD + n] = acc[i][j][q] * (1.0f / 3.0f);
                }
            }
}

// ---------------- rel_out = rel_embed @ w_rel ------------------------------
__global__ __launch_bounds__(256) void k_relout(const float* __restrict__ rel,
                                                const float* __restrict__ w_rel,
                                                float* __restrict__ out) {
    int idx = blockIdx.x * 256 + threadIdx.x;
    if (idx >= N_RELS * HD) return;
    int i = idx >> 7, c = idx & 127;
    float acc = 0.0f;
    for (int k = 0; k < HD; ++k) acc += rel[i * HD + k] * w_rel[k * HD + c];
    out[idx] = acc;
}

extern "C" void kernel_launch(void* const* d_in, const int* in_sizes, int n_in,
                              void* d_out, int out_size, void* d_ws, size_t ws_size,
                              hipStream_t stream) {
    const float* x        = (const float*)d_in[0];
    const int*   ei       = (const int*)d_in[1];
    const int*   et       = (const int*)d_in[2];
    const float* rel      = (const float*)d_in[3];
    const float* w_loop   = (const float*)d_in[4];
    const float* w_in     = (const float*)d_in[5];
    const float* w_out    = (const float*)d_in[6];
    const float* w_rel    = (const float*)d_in[7];
    const float* loop_rel = (const float*)d_in[8];

    char* w = (char*)d_ws;
    ushort_t* Ain  = (ushort_t*)w;  w += (size_t)2 * MPAD * DD * 2;
    ushort_t* xb   = (ushort_t*)w;  w += (size_t)MPAD * DD * 2;
    ushort_t* Wt   = (ushort_t*)w;  w += 256 * 768 * 2;
    uint_t* u      = (uint_t*)w;    w += N_RELS * HD * 4;
    int* deg_i     = (int*)w;       w += NK * 4;
    int* cnt       = (int*)w;       w += NK * 4;
    int* off       = (int*)w;       w += NK * 4;
    int* bsum      = (int*)w;       w += 128 * 4;
    float* dinv    = (float*)w;     w += NK * 4;
    uint_t* bucket = (uint_t*)w;    w += (size_t)ETOT * 4;
    ushort_t* Aout = Ain + (size_t)MPAD * DD;

    float* out     = (float*)d_out;
    float* rel_out = out + (size_t)N_ENT * DD;

    // zero deg_i + cnt (adjacent)
    hipMemsetAsync(deg_i, 0, (size_t)2 * NK * 4, stream);

    k_deg   <<<(ETOT + 255) / 256, 256, 0, stream>>>(ei, deg_i);
    k_scan1 <<<NBLK, 256, 0, stream>>>(deg_i, off, bsum, dinv);
    k_scan2 <<<1, 128, 0, stream>>>(bsum);
    k_bucket<<<(ETOT + 255) / 256, 256, 0, stream>>>(ei, et, off, bsum, cnt, bucket);
    k_prep  <<<12500 + 250 + 768, 256, 0, stream>>>(x, rel, w_in, w_out, w_loop,
                                                    loop_rel, xb, u, Wt);
    k_gather<<<(NK + 3) / 4, 256, 0, stream>>>(bucket, off, bsum, deg_i, dinv, xb, u, Ain);

    dim3 gg(MPAD / 128, 2);
    k_gemm  <<<gg, 256, 0, stream>>>(Ain, Aout, xb, Wt, out);
    k_relout<<<(N_RELS * HD + 255) / 256, 256, 0, stream>>>(rel, w_rel, rel_out);
}

// Round 4
// 183.321 us; speedup vs baseline: 4.1026x; 1.0173x over previous
//
#include <hip/hip_runtime.h>

#define N_ENT 50000
#define MPAD  50048            // 391*128, padded rows for GEMM staging
#define N_RELS 500
#define DD 256
#define HD 128
#define EPD 250000
#define ETOT 500000
#define NK (2 * N_ENT)         // (dir,row) keys
#define NBLK 98                // ceil(NK/1024)
#define REL_SCALE 2.0943951023931953f  // pi / 1.5

typedef unsigned short ushort_t;
typedef unsigned int uint_t;
typedef __attribute__((ext_vector_type(2))) _Float16 h2;
typedef __attribute__((ext_vector_type(8))) _Float16 h8;
typedef __attribute__((ext_vector_type(4))) float f32x4;

__device__ inline uint_t pkh2(float a, float b) {
    union { _Float16 h[2]; uint_t u; } v;
    v.h[0] = (_Float16)a; v.h[1] = (_Float16)b; return v.u;
}
__device__ inline h2 bch2(uint_t w) {
    union { uint_t u; h2 h; } v; v.u = w; return v.h;
}

#if __has_builtin(__builtin_amdgcn_fdot2)
#define FDOT2(a, b, c) __builtin_amdgcn_fdot2((a), (b), (c), false)
#else
__device__ inline float FDOT2(h2 a, h2 b, float c) {
    return c + (float)a[0] * (float)b[0] + (float)a[1] * (float)b[1];
}
#endif

#define GLOAD_LDS16(g, l) __builtin_amdgcn_global_load_lds( \
    (const __attribute__((address_space(1))) unsigned int*)(g), \
    (__attribute__((address_space(3))) unsigned int*)(l), 16, 0, 0)

// ---------------- int degree histogram per (dir,row) -----------------------
__global__ __launch_bounds__(256) void k_deg(const int* __restrict__ ei,
                                             int* __restrict__ deg) {
    int e = blockIdx.x * 256 + threadIdx.x;
    if (e >= ETOT) return;
    int key = (e >= EPD ? N_ENT : 0) + ei[e];
    atomicAdd(deg + key, 1);
}

// ---------------- per-block exclusive scan + dinv --------------------------
__global__ __launch_bounds__(256) void k_scan1(const int* __restrict__ deg,
                                               int* __restrict__ off,
                                               int* __restrict__ bsum,
                                               float* __restrict__ dinv) {
    __shared__ int wsum[4];
    int b = blockIdx.x, t = threadIdx.x;
    int base = b * 1024 + t * 4;
    int v[4];
#pragma unroll
    for (int i = 0; i < 4; ++i) v[i] = (base + i < NK) ? deg[base + i] : 0;
    int tsum = v[0] + v[1] + v[2] + v[3];
    int lane = t & 63, w = t >> 6;
    int incl = tsum;
    for (int d = 1; d < 64; d <<= 1) {
        int y = __shfl_up(incl, d);
        if (lane >= d) incl += y;
    }
    if (lane == 63) wsum[w] = incl;
    __syncthreads();
    int woff = 0;
    for (int k = 0; k < w; ++k) woff += wsum[k];
    int run = woff + incl - tsum;
#pragma unroll
    for (int i = 0; i < 4; ++i) {
        if (base + i < NK) {
            off[base + i] = run;
            dinv[base + i] = (v[i] > 0) ? rsqrtf((float)v[i]) : 0.0f;
        }
        run += v[i];
    }
    if (t == 255) bsum[b] = woff + incl;   // block total
}

__global__ void k_scan2(int* __restrict__ bsum) {
    __shared__ int s[NBLK];
    int t = threadIdx.x;
    if (t < NBLK) s[t] = bsum[t];
    __syncthreads();
    if (t == 0) {
        int c = 0;
        for (int i = 0; i < NBLK; ++i) { int x = s[i]; s[i] = c; c += x; }
    }
    __syncthreads();
    if (t < NBLK) bsum[t] = s[t];
}

// ---------------- bucket edges by (dir,row): 1 atomic per edge -------------
__global__ __launch_bounds__(256) void k_bucket(const int* __restrict__ ei,
                                                const int* __restrict__ et,
                                                const int* __restrict__ off,
                                                const int* __restrict__ bsum,
                                                int* __restrict__ cnt,
                                                uint_t* __restrict__ bucket) {
    int e = blockIdx.x * 256 + threadIdx.x;
    if (e >= ETOT) return;
    int key = (e >= EPD ? N_ENT : 0) + ei[e];
    int pos = off[key] + bsum[key >> 10] + atomicAdd(cnt + key, 1);
    uint_t col = (uint_t)ei[ETOT + e];
    uint_t t   = (uint_t)et[e];
    bucket[pos] = col | (t << 16);         // col < 65536, t < 512
}

// ---------------- prep: xc interleave (25000) + utab (250) + wcat (768) ----
// xc[col*128 + p] = pack_f16(x[col][p], x[col][p+128])
// utab[t*256 + 4l .. +3] = {cs(2l), cs(2l+1), snc(2l), snc(2l+1)}
//   cs(j) = pack(cos_j, sin_j), snc(j) = pack(sin_j, -cos_j)
__global__ __launch_bounds__(256) void k_prep(const float* __restrict__ x,
                                              const float* __restrict__ rel,
                                              const float* __restrict__ w_in,
                                              const float* __restrict__ w_out,
                                              const float* __restrict__ w_loop,
                                              const float* __restrict__ loop_rel,
                                              uint_t* __restrict__ xc,
                                              uint_t* __restrict__ utab,
                                              ushort_t* __restrict__ Wt) {
    int b = blockIdx.x, tid = threadIdx.x;
    if (b < 25000) {                       // xc: one pair per thread
        int idx = b * 256 + tid;           // < 6,400,000 ; col = idx>>7, p = idx&127
        int col = idx >> 7, p = idx & 127;
        float f0 = x[col * DD + p];
        float f1 = x[col * DD + p + HD];
        xc[idx] = pkh2(f0, f1);
    } else if (b < 25250) {                // utab
        int idx = (b - 25000) * 256 + tid; // < 64000 = 500*128
        int t = idx >> 7, j = idx & 127;
        float s, c;
        __sincosf(rel[idx] * REL_SCALE, &s, &c);
        uint_t* U = utab + t * 256 + (j >> 1) * 4 + (j & 1);
        U[0] = pkh2(c, s);
        U[2] = pkh2(s, -c);
    } else {                               // Wt[256n][768k] f16
        int idx = (b - 25250) * 256 + tid; // < 196608
        int n = idx / 768, k = idx - n * 768;
        float v;
        if (k < 256) {
            v = w_in[k * 256 + n];
        } else if (k < 512) {
            v = w_out[(k - 256) * 256 + n];
        } else {
            // third A-block is xc (interleaved): elem kk=2p -> x[p], kk=2p+1 -> x[p+128]
            int kk = k - 512;
            int jj = kk >> 1;
            float s, c;
            __sincosf(loop_rel[jj] * REL_SCALE, &s, &c);
            float w0 = w_loop[jj * 256 + n];
            float w1 = w_loop[(jj + HD) * 256 + n];
            v = ((kk & 1) == 0) ? (c * w0 + s * w1) : (s * w0 - c * w1);
        }
        union { _Float16 h; ushort_t u; } cv; cv.h = (_Float16)v;
        Wt[idx] = cv.u;
    }
}

// ---------------- gather: one wave per (dir,row), f16 dot2 -----------------
// lane l owns complex pairs j=2l, 2l+1:
//   out_lo[j] = re*c + im*s = (re,im).(c,s)   -> A elem j
//   out_hi[j] = re*s - im*c = (re,im).(s,-c)  -> A elem j+128
__global__ __launch_bounds__(256) void k_gather(const uint_t* __restrict__ bucket,
                                                const int* __restrict__ off,
                                                const int* __restrict__ bsum,
                                                const int* __restrict__ deg,
                                                const float* __restrict__ dinv,
                                                const uint_t* __restrict__ xc,
                                                const uint_t* __restrict__ utab,
                                                ushort_t* __restrict__ A) {
    int wid  = (blockIdx.x * 256 + threadIdx.x) >> 6;
    int lane = threadIdx.x & 63;
    if (wid >= NK) return;
    int dir = (wid >= N_ENT);
    int row = wid - dir * N_ENT;
    float dv_r = dinv[wid];
    int start = off[wid] + bsum[wid >> 10];
    int n = deg[wid];
    const float* dvc = dinv + dir * N_ENT;
    float acc0 = 0.f, acc1 = 0.f, acc2 = 0.f, acc3 = 0.f;

#define EDGE_DO(P) do {                                                     \
        int c_ = (int)((P) & 0xFFFFu), t_ = (int)((P) >> 16);               \
        float nm_ = dv_r * dvc[c_];                                         \
        uint2 xw_ = *(const uint2*)(xc + (size_t)c_ * HD + 2 * lane);       \
        uint4 uw_ = *(const uint4*)(utab + (size_t)t_ * 256 + 4 * lane);    \
        h2 nm2_; nm2_[0] = (_Float16)nm_; nm2_[1] = nm2_[0];                \
        h2 a0_ = bch2(xw_.x) * nm2_;                                        \
        h2 a1_ = bch2(xw_.y) * nm2_;                                        \
        acc0 = FDOT2(a0_, bch2(uw_.x), acc0);                               \
        acc1 = FDOT2(a1_, bch2(uw_.y), acc1);                               \
        acc2 = FDOT2(a0_, bch2(uw_.z), acc2);                               \
        acc3 = FDOT2(a1_, bch2(uw_.w), acc3);                               \
    } while (0)

    int i = 0;
    for (; i + 3 < n; i += 4) {
        uint_t p0 = bucket[start + i];
        uint_t p1 = bucket[start + i + 1];
        uint_t p2 = bucket[start + i + 2];
        uint_t p3 = bucket[start + i + 3];
        EDGE_DO(p0); EDGE_DO(p1); EDGE_DO(p2); EDGE_DO(p3);
    }
    for (; i < n; ++i) {
        uint_t p0 = bucket[start + i];
        EDGE_DO(p0);
    }
#undef EDGE_DO

    uint_t* Ar = (uint_t*)(A + (size_t)(dir * MPAD + row) * DD);
    Ar[lane]      = pkh2(acc0, acc1);   // elems 2l, 2l+1
    Ar[64 + lane] = pkh2(acc2, acc3);   // elems 128+2l, 128+2l+1
}

// ---------------- MFMA GEMM: out = [Ain|Aout|xc](M x 768) @ Wt^T / 3 -------
__global__ __launch_bounds__(256) void k_gemm(const ushort_t* __restrict__ Ain,
                                              const ushort_t* __restrict__ Aout,
                                              const ushort_t* __restrict__ xcf,
                                              const ushort_t* __restrict__ Wt,
                                              float* __restrict__ out) {
    __shared__ ushort_t Al[128 * 32];
    __shared__ ushort_t Bl[128 * 32];
    int tid = threadIdx.x;
    int m0 = blockIdx.x * 128, n0 = blockIdx.y * 128;
    int lane = tid & 63, wv = tid >> 6;
    int wr = (wv >> 1) * 64, wc = (wv & 1) * 64;
    int srow = tid >> 2;            // 0..63
    int scol = (tid & 3) * 8;       // k elems
    f32x4 zero = {0.f, 0.f, 0.f, 0.f};
    f32x4 acc[4][4];
#pragma unroll
    for (int i = 0; i < 4; ++i)
#pragma unroll
        for (int j = 0; j < 4; ++j) acc[i][j] = zero;

    for (int k0 = 0; k0 < 768; k0 += 32) {
        const ushort_t* baseA = (k0 < 256) ? Ain : ((k0 < 512) ? Aout : xcf);
        int kk0 = k0 & 255;
        GLOAD_LDS16(baseA + (size_t)(m0 + srow) * DD + kk0 + scol,      &Al[tid * 8]);
        GLOAD_LDS16(baseA + (size_t)(m0 + 64 + srow) * DD + kk0 + scol, &Al[2048 + tid * 8]);
        GLOAD_LDS16(Wt + (size_t)(n0 + srow) * 768 + k0 + scol,         &Bl[tid * 8]);
        GLOAD_LDS16(Wt + (size_t)(n0 + 64 + srow) * 768 + k0 + scol,    &Bl[2048 + tid * 8]);
        __syncthreads();
        int r = lane & 15, h = lane >> 4;
        h8 a[4], b[4];
#pragma unroll
        for (int i = 0; i < 4; ++i) a[i] = *(const h8*)&Al[(wr + i * 16 + r) * 32 + h * 8];
#pragma unroll
        for (int j = 0; j < 4; ++j) b[j] = *(const h8*)&Bl[(wc + j * 16 + r) * 32 + h * 8];
#pragma unroll
        for (int i = 0; i < 4; ++i)
#pragma unroll
            for (int j = 0; j < 4; ++j)
                acc[i][j] = __builtin_amdgcn_mfma_f32_16x16x32_f16(a[i], b[j], acc[i][j], 0, 0, 0);
        __syncthreads();
    }
    // C/D: col = lane&15, row = (lane>>4)*4 + reg (dtype-independent)
    int cn = lane & 15, rq = lane >> 4;
#pragma unroll
    for (int i = 0; i < 4; ++i)
#pragma unroll
        for (int j = 0; j < 4; ++j)
#pragma unroll
            for (int q = 0; q < 4; ++q) {
                int m = m0 + wr + i * 16 + rq * 4 + q;
                if (m < N_ENT) {
                    int n = n0 + wc + j * 16 + cn;
                    out[(size_t)m * DD + n] = acc[i][j][q] * (1.0f / 3.0f);
                }
            }
}

// ---------------- rel_out = rel_embed @ w_rel ------------------------------
__global__ __launch_bounds__(256) void k_relout(const float* __restrict__ rel,
                                                const float* __restrict__ w_rel,
                                                float* __restrict__ out) {
    int idx = blockIdx.x * 256 + threadIdx.x;
    if (idx >= N_RELS * HD) return;
    int i = idx >> 7, c = idx & 127;
    float acc = 0.0f;
    for (int k = 0; k < HD; ++k) acc += rel[i * HD + k] * w_rel[k * HD + c];
    out[idx] = acc;
}

extern "C" void kernel_launch(void* const* d_in, const int* in_sizes, int n_in,
                              void* d_out, int out_size, void* d_ws, size_t ws_size,
                              hipStream_t stream) {
    const float* x        = (const float*)d_in[0];
    const int*   ei       = (const int*)d_in[1];
    const int*   et       = (const int*)d_in[2];
    const float* rel      = (const float*)d_in[3];
    const float* w_loop   = (const float*)d_in[4];
    const float* w_in     = (const float*)d_in[5];
    const float* w_out    = (const float*)d_in[6];
    const float* w_rel    = (const float*)d_in[7];
    const float* loop_rel = (const float*)d_in[8];

    char* w = (char*)d_ws;
    ushort_t* A    = (ushort_t*)w;  w += (size_t)2 * MPAD * DD * 2;   // f16 [2][MPAD][DD]
    uint_t* xc     = (uint_t*)w;    w += (size_t)N_ENT * HD * 4;      // packed pairs
    ushort_t* Wt   = (ushort_t*)w;  w += 256 * 768 * 2;
    uint_t* utab   = (uint_t*)w;    w += N_RELS * 256 * 4;
    int* deg_i     = (int*)w;       w += NK * 4;
    int* cnt       = (int*)w;       w += NK * 4;
    int* off       = (int*)w;       w += NK * 4;
    int* bsum      = (int*)w;       w += 128 * 4;
    float* dinv    = (float*)w;     w += NK * 4;
    uint_t* bucket = (uint_t*)w;    w += (size_t)ETOT * 4;
    ushort_t* Aout = A + (size_t)MPAD * DD;

    float* out     = (float*)d_out;
    float* rel_out = out + (size_t)N_ENT * DD;

    // zero deg_i + cnt (adjacent)
    hipMemsetAsync(deg_i, 0, (size_t)2 * NK * 4, stream);

    k_deg   <<<(ETOT + 255) / 256, 256, 0, stream>>>(ei, deg_i);
    k_scan1 <<<NBLK, 256, 0, stream>>>(deg_i, off, bsum, dinv);
    k_scan2 <<<1, 128, 0, stream>>>(bsum);
    k_bucket<<<(ETOT + 255) / 256, 256, 0, stream>>>(ei, et, off, bsum, cnt, bucket);
    k_prep  <<<25000 + 250 + 768, 256, 0, stream>>>(x, rel, w_in, w_out, w_loop,
                                                    loop_rel, xc, utab, Wt);
    k_gather<<<(NK + 3) / 4, 256, 0, stream>>>(bucket, off, bsum, deg_i, dinv,
                                               xc, utab, A);

    dim3 gg(MPAD / 128, 2);
    k_gemm  <<<gg, 256, 0, stream>>>(A, Aout, (const ushort_t*)xc, Wt, out);
    k_relout<<<(N_RELS * HD + 255) / 256, 256, 0, stream>>>(rel, w_rel, rel_out);
}